// Round 10
// baseline (3228.709 us; speedup 1.0000x reference)
//
#include <hip/hip_runtime.h>
#include <cstdint>
#include <cstddef>
#include <cstring>

#define LSEQ 512
#define BATCH 64
#define DIM 256
#define HID 256
#define NTAG 11

typedef float vf4 __attribute__((ext_vector_type(4)));

// ---------------- input GEMM (+embedding gather, +bias) ----------------
// Gin float layout per (dir,t): [b(64)][e(256)][gate(4)] — lstm_rec lane
// reads one float4 = the 4 gate preacts of (e, batch).
__global__ void __launch_bounds__(256) gemm_in(
    const int* __restrict__ sent, const float* __restrict__ emb,
    const float* __restrict__ Wf, const float* __restrict__ bf,
    const float* __restrict__ Wb, const float* __restrict__ bb,
    float* __restrict__ Gin, int t0, int CT)
{
    const int mt = blockIdx.x, nt = blockIdx.y, dir = blockIdx.z;
    const float* __restrict__ W    = dir ? Wb : Wf;
    const float* __restrict__ bias = dir ? bb : bf;
    const int tid = threadIdx.x;
    const int tx = tid & 15, ty = tid >> 4;

    __shared__ float As[128][36];
    __shared__ float Bs[128][36];

    const float* arow[4];
    const float* brow[4];
#pragma unroll
    for (int j = 0; j < 4; j++) {
        int v  = j * 256 + tid;
        int mi = v >> 3;
        int m_g = mt * 128 + mi;
        int b = m_g & 63, tl = m_g >> 6;
        int tg = t0 + tl;
        int tt = dir ? (LSEQ - 1 - tg) : tg;
        int tok = sent[b * LSEQ + tt];
        arow[j] = emb + (size_t)tok * DIM;
        brow[j] = W + (size_t)(nt * 128 + mi) * DIM;
    }

    float acc[8][8];
#pragma unroll
    for (int i = 0; i < 8; i++)
#pragma unroll
        for (int j = 0; j < 8; j++) acc[i][j] = 0.f;

    for (int ki = 0; ki < 8; ki++) {
        const int k0 = ki * 32;
        __syncthreads();
#pragma unroll
        for (int j = 0; j < 4; j++) {
            int v  = j * 256 + tid;
            int mi = v >> 3, k4 = v & 7;
            float4 av = *(const float4*)(arow[j] + k0 + k4 * 4);
            float4 bv = *(const float4*)(brow[j] + k0 + k4 * 4);
            *(float4*)&As[mi][k4 * 4] = av;
            *(float4*)&Bs[mi][k4 * 4] = bv;
        }
        __syncthreads();
#pragma unroll
        for (int k = 0; k < 32; k++) {
            float a[8], bv[8];
#pragma unroll
            for (int i = 0; i < 8; i++) a[i] = As[ty + 16 * i][k];
#pragma unroll
            for (int j = 0; j < 8; j++) bv[j] = Bs[tx + 16 * j][k];
#pragma unroll
            for (int i = 0; i < 8; i++)
#pragma unroll
                for (int j = 0; j < 8; j++) acc[i][j] = fmaf(a[i], bv[j], acc[i][j]);
        }
    }
#pragma unroll
    for (int i = 0; i < 8; i++) {
        int m_g = mt * 128 + ty + 16 * i;
        int b = m_g & 63, tl = m_g >> 6;
        size_t base = ((size_t)(dir * CT + tl) * 64 + b) * 1024;
#pragma unroll
        for (int j = 0; j < 8; j++) {
            int n = nt * 128 + tx + 16 * j;
            int q = n >> 8, e = n & 255;
            Gin[base + e * 4 + q] = acc[i][j] + bias[n];
        }
    }
}

// ---------------- persistent bidirectional LSTM recurrence ----------------
// 256 WGs (256 thr) = 32 groups x 8 members; member w owns elems [32w,+32).
// Thread (wave wv, lane = rg*8+kq): owns the 4 GATE-ROWS of elem
// e = 32w+8wv+rg over k-chunk [32kq,+32) — 4x8 f4 = 128 weight VGPRs — for
// ALL 4 batches. Each h float4 LDS read feeds 16 FMAs (was 4 in R8/R9:
// 128 reads/thread-step -> 32), and the chunk-stride-36 padding puts the 8
// kq addresses on distinct banks (R9's 1.34e8 conflicts came from the
// 512B-apart dual-address b128 reads, NOT the shuffles).
// Reduction over 8 kq lanes: value-halving shuffles (masks 1,2,4);
// lane ends with the 4 gates of (e, batch beta=2*(kq&1)+((kq>>1)&1)),
// duplicated over kq bit2.
// TAG-IN-DATA exchange (single MALL RT) + ONE __syncthreads per step.
__global__ void __launch_bounds__(256, 1) lstm_rec(
    const float* __restrict__ Gin,
    const float* __restrict__ Whh_f, const float* __restrict__ Whh_b,
    const float* __restrict__ h0, const float* __restrict__ c0,
    float* __restrict__ hs, unsigned long long* __restrict__ htag,
    float* __restrict__ cbuf, int t0, int CT)
{
    const int wg = blockIdx.x;
    const int w = wg >> 5, g = wg & 31;
    const int dir   = g >> 4;
    const int bbase = (g & 15) << 2;
    const int tid = threadIdx.x;
    const int wv = tid >> 6, lane = tid & 63;
    const int rg = lane >> 3, kq = lane & 7;
    const int e = (w << 5) + (wv << 3) + rg;          // elem [0,256)
    const int kb1 = (kq >> 1) & 1;
    const int beta = ((kq & 1) << 1) + kb1;           // batch after reduction
    const float* __restrict__ Whh = dir ? Whh_b : Whh_f;

    // weights: 4 gate-rows of elem e, k-chunk [32kq,+32) = 128 VGPRs
    vf4 wreg[4][8];
#pragma unroll
    for (int q = 0; q < 4; q++) {
        const vf4* wp = (const vf4*)(Whh + (size_t)((q << 8) + e) * HID + (kq << 5));
#pragma unroll
        for (int i = 0; i < 8; i++) wreg[q][i] = wp[i];
    }
#pragma unroll
    for (int q = 0; q < 4; q++)
#pragma unroll
        for (int i = 0; i < 8; i++) asm volatile("" : "+v"(wreg[q][i]));

    // h buffers: [slot][batch][chunk(8) * stride 36] — banks 4*kq: conflict-free
    __shared__ float Hl[2][4][288];

    float c = ((t0 == 0) ? c0 : cbuf)[((size_t)dir * BATCH + bbase + beta) * HID + e];

    const int sb = tid >> 6, k4 = tid & 63;           // staging: batch, f4-slot

    const float4* __restrict__ Gin4 = (const float4*)Gin;
    const size_t gin_off = ((size_t)(dir * CT) * 64 + bbase + beta) * 256 + e;
    float4 gv = Gin4[gin_off];                        // t_local = 0

    for (int t = t0; t < t0 + CT; t++) {
        const int wslot = t & 1;

        // ---- stage h(t-1): poll tagged data words (single-RT consume) ----
        {
            float4 hv;
            if (t == 0) {
                hv = ((const float4*)(h0 + ((size_t)dir * BATCH + bbase + sb) * HID))[k4];
            } else {
                const unsigned long long* hp =
                    htag + ((((size_t)((t - 1) & 1) * 2 + dir) * BATCH + bbase + sb) * HID
                            + k4 * 4);
                const unsigned int tg = (unsigned int)t;
                unsigned long long u0, u1, u2, u3;
                for (;;) {
                    u0 = __hip_atomic_load(hp + 0, __ATOMIC_RELAXED, __HIP_MEMORY_SCOPE_AGENT);
                    u1 = __hip_atomic_load(hp + 1, __ATOMIC_RELAXED, __HIP_MEMORY_SCOPE_AGENT);
                    u2 = __hip_atomic_load(hp + 2, __ATOMIC_RELAXED, __HIP_MEMORY_SCOPE_AGENT);
                    u3 = __hip_atomic_load(hp + 3, __ATOMIC_RELAXED, __HIP_MEMORY_SCOPE_AGENT);
                    if (((unsigned int)(u0 >> 32) == tg) & ((unsigned int)(u1 >> 32) == tg) &
                        ((unsigned int)(u2 >> 32) == tg) & ((unsigned int)(u3 >> 32) == tg))
                        break;
                    __builtin_amdgcn_s_sleep(1);
                }
                hv.x = __uint_as_float((unsigned int)u0);
                hv.y = __uint_as_float((unsigned int)u1);
                hv.z = __uint_as_float((unsigned int)u2);
                hv.w = __uint_as_float((unsigned int)u3);
            }
            // padded store: elems 4*k4..+3 -> chunk k4>>3, offset 4*(k4&7)
            *(float4*)&Hl[wslot][sb][(k4 >> 3) * 36 + ((k4 & 7) << 2)] = hv;
        }
        __syncthreads();

        // prefetch Gin for t+1 (overlaps GEMV)
        int tln = t + 1 - t0; if (tln >= CT) tln = CT - 1;
        const float4 gvn = Gin4[gin_off + (size_t)tln * 16384];

        // ---- GEMV: 4 gates x 4 batches x 32-k; 32 conflict-free LDS reads ----
        float acc[4][4];
#pragma unroll
        for (int q = 0; q < 4; q++)
#pragma unroll
            for (int b = 0; b < 4; b++) acc[q][b] = 0.f;
#pragma unroll
        for (int i = 0; i < 8; i++) {
#pragma unroll
            for (int b = 0; b < 4; b++) {
                const float4 hb = *(const float4*)&Hl[wslot][b][kq * 36 + (i << 2)];
#pragma unroll
                for (int q = 0; q < 4; q++) {
                    acc[q][b] = fmaf(wreg[q][i][0], hb.x, acc[q][b]);
                    acc[q][b] = fmaf(wreg[q][i][1], hb.y, acc[q][b]);
                    acc[q][b] = fmaf(wreg[q][i][2], hb.z, acc[q][b]);
                    acc[q][b] = fmaf(wreg[q][i][3], hb.w, acc[q][b]);
                }
            }
        }

        // ---- reduce over 8 kq lanes (value-halving, static masks) ----
        const int pkeep = kq & 1;                 // batch-pair {2p, 2p+1}
        float s1[4][2];
#pragma unroll
        for (int q = 0; q < 4; q++)
#pragma unroll
            for (int m = 0; m < 2; m++) {
                const float mine = acc[q][2 * pkeep + m];
                const float give = acc[q][2 * (1 - pkeep) + m];
                s1[q][m] = mine + __shfl_xor(give, 1, 64);
            }
        float s2[4];
#pragma unroll
        for (int q = 0; q < 4; q++) {
            const float mine = s1[q][kb1];
            const float give = s1[q][1 - kb1];
            s2[q] = mine + __shfl_xor(give, 2, 64);
        }
        float v[4];
#pragma unroll
        for (int q = 0; q < 4; q++)
            v[q] = s2[q] + __shfl_xor(s2[q], 4, 64);
        // v[0..3] = preacts i,f,g,o of (elem e, batch bbase+beta)

        v[0] += gv.x; v[1] += gv.y; v[2] += gv.z; v[3] += gv.w;
        gv = gvn;

        c = (1.f / (1.f + expf(-v[1]))) * c + (1.f / (1.f + expf(-v[0]))) * tanhf(v[2]);
        const float h = (1.f / (1.f + expf(-v[3]))) * tanhf(c);

        if (kq < 4) {
            const int t_orig = dir ? (LSEQ - 1 - t) : t;
            const unsigned long long pkt =
                ((unsigned long long)(unsigned int)(t + 1) << 32)
                | (unsigned long long)__float_as_uint(h);
            __hip_atomic_store(
                &htag[(((size_t)wslot * 2 + dir) * BATCH + bbase + beta) * HID + e],
                pkt, __ATOMIC_RELAXED, __HIP_MEMORY_SCOPE_AGENT);
            hs[((size_t)(dir * LSEQ + t_orig) * BATCH + bbase + beta) * HID + e] = h;
        }
    }
    if (kq < 4)
        cbuf[((size_t)dir * BATCH + bbase + beta) * HID + e] = c;
}

// ---------------- output projection: logits[b][t][11] ----------------
__global__ void __launch_bounds__(256) logits_k(
    const float* __restrict__ hs, const float* __restrict__ Wout,
    const float* __restrict__ bout, float* __restrict__ logits)
{
    const int tid = threadIdx.x;
    const int rt = tid >> 4, tg = tid & 15;
    __shared__ float hrow[16][516];
    __shared__ float Wl[NTAG][516];
    const int rbase = blockIdx.x * 16;

#pragma unroll
    for (int i = 0; i < 8; i++) {
        int u  = tid + i * 256;
        int rr = u >> 7, c4 = u & 127;
        int r_g = rbase + rr;
        int b = r_g >> 9, t = r_g & 511;
        int d = (c4 >= 64) ? 1 : 0, k4 = c4 & 63;
        float4 hv = ((const float4*)hs)[(((size_t)d * LSEQ + t) * BATCH + b) * 64 + k4];
        *(float4*)&hrow[rr][c4 * 4] = hv;
    }
    for (int u = tid; u < NTAG * 128; u += 256) {
        int row = u >> 7, c4 = u & 127;
        float4 wv = ((const float4*)Wout)[(size_t)row * 128 + c4];
        *(float4*)&Wl[row][c4 * 4] = wv;
    }
    __syncthreads();

    if (tg < NTAG) {
        const float4* hp = (const float4*)&hrow[rt][0];
        const float4* wp = (const float4*)&Wl[tg][0];
        float acc = 0.f;
#pragma unroll 4
        for (int k = 0; k < 128; k++) {
            float4 h = hp[k], ww = wp[k];
            acc = fmaf(h.x, ww.x, acc); acc = fmaf(h.y, ww.y, acc);
            acc = fmaf(h.z, ww.z, acc); acc = fmaf(h.w, ww.w, acc);
        }
        int r_g = rbase + rt;
        logits[(size_t)r_g * NTAG + tg] = acc + bout[tg];
    }
}

// ---------------- Viterbi (one wave per batch element) ----------------
__global__ void __launch_bounds__(64) viterbi_k(
    const float* __restrict__ logits, const float* __restrict__ trans,
    float* __restrict__ out)
{
    const int b = blockIdx.x, lane = threadIdx.x;
    __shared__ float lgl[LSEQ * NTAG];
    __shared__ unsigned char bp[LSEQ][16];
    __shared__ float pathf[LSEQ];

    {
        const float4* src = (const float4*)(logits + (size_t)b * LSEQ * NTAG);
        float4* dst = (float4*)lgl;
        for (int u = lane; u < (LSEQ * NTAG) / 4; u += 64) dst[u] = src[u];
    }
    float tcol[NTAG];
    if (lane < NTAG) {
#pragma unroll
        for (int i = 0; i < NTAG; i++) tcol[i] = trans[i * NTAG + lane];
    }
    __syncthreads();

    float v = (lane < NTAG) ? lgl[lane] : -1e30f;
    for (int t = 1; t < LSEQ; t++) {
        float best = -1e30f; int bi = 0;
#pragma unroll
        for (int i = 0; i < NTAG; i++) {
            float vi = __shfl(v, i, 64) + tcol[i];
            if (vi > best) { best = vi; bi = i; }   // strict > == first-max
        }
        if (lane < NTAG) {
            v = lgl[t * NTAG + lane] + best;
            bp[t][lane] = (unsigned char)bi;
        }
    }
    float bestv = -1e30f; int bestj = 0;
#pragma unroll
    for (int j = 0; j < NTAG; j++) {
        float vj = __shfl(v, j, 64);
        if (vj > bestv) { bestv = vj; bestj = j; }
    }
    if (lane == 0) {
        out[b] = bestv;
        int st = bestj;
        pathf[LSEQ - 1] = (float)st;
        for (int t = LSEQ - 1; t >= 1; t--) { st = bp[t][st]; pathf[t - 1] = (float)st; }
    }
    __syncthreads();
    for (int t = lane; t < LSEQ; t += 64)
        out[BATCH + (size_t)b * LSEQ + t] = pathf[t];
}

// ---------------- host ----------------
extern "C" void kernel_launch(void* const* d_in, const int* in_sizes, int n_in,
                              void* d_out, int out_size, void* d_ws, size_t ws_size,
                              hipStream_t stream)
{
    (void)in_sizes; (void)n_in; (void)out_size;
    const int*   sent  = (const int*)  d_in[0];
    const float* emb   = (const float*)d_in[1];
    const float* Wihf  = (const float*)d_in[2];
    const float* Whhf  = (const float*)d_in[3];
    const float* bf    = (const float*)d_in[4];
    const float* Wihb  = (const float*)d_in[5];
    const float* Whhb  = (const float*)d_in[6];
    const float* bb    = (const float*)d_in[7];
    const float* Wout  = (const float*)d_in[8];
    const float* bout  = (const float*)d_in[9];
    const float* trans = (const float*)d_in[10];
    const float* h0    = (const float*)d_in[11];
    const float* c0    = (const float*)d_in[12];
    float* out = (float*)d_out;

    // ws (floats): Gin[CT*131072] | hs[16777216] | htag[262144 (=131072 u64)]
    //            | cbuf[32768] | logits[360448]
    const size_t fixed = 16777216ull + 262144ull + 32768ull + 360448ull;
    int CT = LSEQ;
    while (CT > 8 && ((size_t)CT * 131072ull + fixed) * 4ull > ws_size) CT >>= 1;

    float* ws = (float*)d_ws;
    size_t off = 0;
    float* Gin  = ws + off; off += (size_t)CT * 131072ull;
    float* hs   = ws + off; off += 16777216ull;
    unsigned long long* htag = (unsigned long long*)(ws + off); off += 262144ull;
    float* cbuf = ws + off; off += 32768ull;
    float* lgts = ws + off; off += 360448ull;

    const int nch = LSEQ / CT;
    for (int c = 0; c < nch; c++) {
        int t0 = c * CT;
        hipLaunchKernelGGL(gemm_in, dim3(CT / 2, 8, 2), dim3(256), 0, stream,
                           sent, emb, Wihf, bf, Wihb, bb, Gin, t0, CT);
        hipLaunchKernelGGL(lstm_rec, dim3(256), dim3(256), 0, stream,
                           Gin, Whhf, Whhb, h0, c0, hs, htag, cbuf, t0, CT);
    }
    hipLaunchKernelGGL(logits_k, dim3((BATCH * LSEQ) / 16), dim3(256), 0, stream,
                       hs, Wout, bout, lgts);
    hipLaunchKernelGGL(viterbi_k, dim3(BATCH), dim3(64), 0, stream,
                       lgts, trans, out);
}

// Round 11
// 2153.745 us; speedup vs baseline: 1.4991x; 1.4991x over previous
//
#include <hip/hip_runtime.h>
#include <cstdint>
#include <cstddef>
#include <cstring>

#define LSEQ 512
#define BATCH 64
#define DIM 256
#define HID 256
#define NTAG 11

typedef float vf4 __attribute__((ext_vector_type(4)));
typedef __bf16 bf16x8 __attribute__((ext_vector_type(8)));
typedef float f32x4 __attribute__((ext_vector_type(4)));
typedef unsigned short u16;

// ---------------- fp32 -> bf16 (RNE) convert ----------------
__global__ void __launch_bounds__(256) cvt_bf16(
    const float* __restrict__ src, u16* __restrict__ dst, int n4)
{
    int i = blockIdx.x * blockDim.x + threadIdx.x;
    const int stride = gridDim.x * blockDim.x;
    for (; i < n4; i += stride) {
        float4 f = ((const float4*)src)[i];
        ushort4 r;
        unsigned int u;
        u = __float_as_uint(f.x); u += 0x7FFFu + ((u >> 16) & 1u); r.x = (u16)(u >> 16);
        u = __float_as_uint(f.y); u += 0x7FFFu + ((u >> 16) & 1u); r.y = (u16)(u >> 16);
        u = __float_as_uint(f.z); u += 0x7FFFu + ((u >> 16) & 1u); r.z = (u16)(u >> 16);
        u = __float_as_uint(f.w); u += 0x7FFFu + ((u >> 16) & 1u); r.w = (u16)(u >> 16);
        ((ushort4*)dst)[i] = r;
    }
}

// ---------------- input GEMM via bf16 MFMA (+gather, +bias) ----------------
// C[m][n] = emb[tok_m][:] . W[n][:], m = tl*64 + b (128 rows/block),
// n = gate-row (128/block). 4 waves: (wm,wn) 2x2, each 4x4 16x16 MFMA tiles.
// Epilogue writes R9's Gin layout: float addr
//   ((dir*CT+tl)*16 + b>>2)*4096 + w*512 + v*128 + jj*16 + q*4 + (b&3)
// with n = q*256 + e, e = w*32 + v*8 + jj.
__global__ void __launch_bounds__(256) gemm_in(
    const int* __restrict__ sent, const u16* __restrict__ embb,
    const u16* __restrict__ w16f, const u16* __restrict__ w16b,
    const float* __restrict__ bf_, const float* __restrict__ bb_,
    float* __restrict__ Gin, int t0, int CT)
{
    const int mtile = blockIdx.x, ntile = blockIdx.y, dir = blockIdx.z;
    const u16* __restrict__ W16 = dir ? w16b : w16f;
    const float* __restrict__ bias = dir ? bb_ : bf_;
    const int tid = threadIdx.x;
    const int wave = tid >> 6, lane = tid & 63;
    const int wm = wave & 1, wn = wave >> 1;

    __shared__ u16 Asm[128][40];   // [m][k] pitch 40 (2-way max on frag reads)
    __shared__ u16 Bsm[128][40];   // [n][k]

    // staging: thread -> (row = tid>>1, half = tid&1), 32B per matrix per k-iter
    const int row = tid >> 1, half = tid & 1;
    const u16* ap;
    {
        int m_g = mtile * 128 + row;
        int tl = m_g >> 6, b = m_g & 63;
        int tg = t0 + tl;
        int tt = dir ? (LSEQ - 1 - tg) : tg;
        ap = embb + (size_t)sent[b * LSEQ + tt] * DIM;
    }
    const u16* bp = W16 + (size_t)(ntile * 128 + row) * DIM;

    f32x4 acc[4][4];
#pragma unroll
    for (int i = 0; i < 4; i++)
#pragma unroll
        for (int j = 0; j < 4; j++) acc[i][j] = (f32x4){0.f, 0.f, 0.f, 0.f};

    const int col = lane & 15, quad = lane >> 4;

    for (int ki = 0; ki < 8; ki++) {
        const int k0 = ki * 32;
        __syncthreads();
        {
            uint4 a0 = *(const uint4*)(ap + k0 + half * 16);
            uint4 a1 = *(const uint4*)(ap + k0 + half * 16 + 8);
            uint4 b0 = *(const uint4*)(bp + k0 + half * 16);
            uint4 b1 = *(const uint4*)(bp + k0 + half * 16 + 8);
            *(uint4*)&Asm[row][half * 16 + 0] = a0;
            *(uint4*)&Asm[row][half * 16 + 8] = a1;
            *(uint4*)&Bsm[row][half * 16 + 0] = b0;
            *(uint4*)&Bsm[row][half * 16 + 8] = b1;
        }
        __syncthreads();

        bf16x8 af[4], bg[4];
#pragma unroll
        for (int i = 0; i < 4; i++) {
            af[i] = *(const bf16x8*)&Asm[wm * 64 + i * 16 + col][quad * 8];
            bg[i] = *(const bf16x8*)&Bsm[wn * 64 + i * 16 + col][quad * 8];
        }
#pragma unroll
        for (int mt = 0; mt < 4; mt++)
#pragma unroll
            for (int nt = 0; nt < 4; nt++)
                acc[mt][nt] = __builtin_amdgcn_mfma_f32_16x16x32_bf16(
                    af[mt], bg[nt], acc[mt][nt], 0, 0, 0);
    }

    // epilogue: C/D map col=lane&15 (n), row=quad*4+reg (m)
#pragma unroll
    for (int nt = 0; nt < 4; nt++) {
        const int n_g = ntile * 128 + wn * 64 + nt * 16 + col;
        const float bv = bias[n_g];
        const int q = n_g >> 8, e = n_g & 255;
        const size_t nOff = (size_t)(e >> 5) * 512 + ((e >> 3) & 3) * 128
                          + (e & 7) * 16 + q * 4;
#pragma unroll
        for (int mt = 0; mt < 4; mt++)
#pragma unroll
            for (int r = 0; r < 4; r++) {
                const int m_g = mtile * 128 + wm * 64 + mt * 16 + quad * 4 + r;
                const int tl = m_g >> 6, b = m_g & 63;
                Gin[((size_t)(dir * CT + tl) * 16 + (b >> 2)) * 4096
                    + nOff + (b & 3)] = acc[mt][nt][r] + bv;
            }
    }
}

// ---------------- persistent bidirectional LSTM recurrence (R9 exact) ------
// 256 WGs (256 thr) = 32 groups x 8 members; member w owns elems [32w,+32).
// Thread (wave wv, lane = jj*8 + q*2 + s): gate-row q*256 + (32w+8wv+jj),
// k-half s -> 32 float4 of weights (compiler streams from L2 — measured
// FASTER than register-pinning, which starves the LDS-load scheduler: R10).
// TAG-IN-DATA exchange: h published as ONE 64-bit agent atomic
// ((t+1)<<32 | h_bits); consumers poll the data word until the tag matches
// => single MALL round trip, no flags, no drains.
__global__ void __launch_bounds__(256, 1) lstm_rec(
    const float* __restrict__ Gin,
    const float* __restrict__ Whh_f, const float* __restrict__ Whh_b,
    const float* __restrict__ h0, const float* __restrict__ c0,
    float* __restrict__ hs, unsigned long long* __restrict__ htag,
    float* __restrict__ cbuf, int t0, int CT)
{
    const int wg = blockIdx.x;
    const int w = wg >> 5, g = wg & 31;
    const int dir   = g >> 4;
    const int bbase = (g & 15) << 2;
    const int tid = threadIdx.x;
    const int wv = tid >> 6, lane = tid & 63;
    const int jj = lane >> 3, q = (lane >> 1) & 3, s = lane & 1;
    const int ee = (w << 5) + (wv << 3) + jj;      // hidden elem [0,256)
    const int row = (q << 8) + ee;                 // gate row [0,1024)
    const float* __restrict__ Whh = dir ? Whh_b : Whh_f;

    vf4 wreg[32];
    {
        const vf4* wp = (const vf4*)(Whh + (size_t)row * HID + s * 128);
#pragma unroll
        for (int i = 0; i < 32; i++) wreg[i] = wp[i];
    }

    __shared__ float4 Hl[2][4][64];                // [slot][batch][f4]

    float c = ((t0 == 0) ? c0 : cbuf)[((size_t)dir * BATCH + bbase + q) * HID + ee];

    const int sb = tid >> 6, k4 = tid & 63;        // staging: batch, f4-slot

    const float4* __restrict__ Gin4 = (const float4*)Gin;
    const size_t gin_thread_off = ((size_t)(dir * CT) * 16 + (bbase >> 2)) * 1024
                                + w * 128 + wv * 32 + jj * 4 + q;
    float4 gv = Gin4[gin_thread_off];              // t_local = 0

    const bool qb0 = (lane & 2) != 0;
    const bool qb1 = (lane & 4) != 0;

    for (int t = t0; t < t0 + CT; t++) {
        const int wslot = t & 1;

        // ---- stage h(t-1): poll tagged data words (single-RT consume) ----
        {
            float4 hv;
            if (t == 0) {
                hv = ((const float4*)(h0 + ((size_t)dir * BATCH + bbase + sb) * HID))[k4];
            } else {
                const unsigned long long* hp =
                    htag + ((((size_t)((t - 1) & 1) * 2 + dir) * BATCH + bbase + sb) * HID
                            + k4 * 4);
                const unsigned int tg = (unsigned int)t;
                unsigned long long u0, u1, u2, u3;
                for (;;) {
                    u0 = __hip_atomic_load(hp + 0, __ATOMIC_RELAXED, __HIP_MEMORY_SCOPE_AGENT);
                    u1 = __hip_atomic_load(hp + 1, __ATOMIC_RELAXED, __HIP_MEMORY_SCOPE_AGENT);
                    u2 = __hip_atomic_load(hp + 2, __ATOMIC_RELAXED, __HIP_MEMORY_SCOPE_AGENT);
                    u3 = __hip_atomic_load(hp + 3, __ATOMIC_RELAXED, __HIP_MEMORY_SCOPE_AGENT);
                    if (((unsigned int)(u0 >> 32) == tg) & ((unsigned int)(u1 >> 32) == tg) &
                        ((unsigned int)(u2 >> 32) == tg) & ((unsigned int)(u3 >> 32) == tg))
                        break;
                    __builtin_amdgcn_s_sleep(1);
                }
                hv.x = __uint_as_float((unsigned int)u0);
                hv.y = __uint_as_float((unsigned int)u1);
                hv.z = __uint_as_float((unsigned int)u2);
                hv.w = __uint_as_float((unsigned int)u3);
            }
            Hl[wslot][sb][k4] = hv;
        }
        __syncthreads();

        // prefetch Gin for t+1
        int tln = t + 1 - t0; if (tln >= CT) tln = CT - 1;
        const float4 gvn = Gin4[gin_thread_off + (size_t)tln * 16384];

        // ---- GEMV: 1 row-half x 4 batches from LDS broadcast ----
        float p0 = 0.f, p1 = 0.f, p2 = 0.f, p3 = 0.f;
        const float4* h0p = &Hl[wslot][0][s * 32];
        const float4* h1p = &Hl[wslot][1][s * 32];
        const float4* h2p = &Hl[wslot][2][s * 32];
        const float4* h3p = &Hl[wslot][3][s * 32];
#pragma unroll
        for (int i = 0; i < 32; i++) {
            const vf4 wvv = wreg[i];
            float4 hv;
            hv = h0p[i];
            p0 = fmaf(wvv[0], hv.x, p0); p0 = fmaf(wvv[1], hv.y, p0);
            p0 = fmaf(wvv[2], hv.z, p0); p0 = fmaf(wvv[3], hv.w, p0);
            hv = h1p[i];
            p1 = fmaf(wvv[0], hv.x, p1); p1 = fmaf(wvv[1], hv.y, p1);
            p1 = fmaf(wvv[2], hv.z, p1); p1 = fmaf(wvv[3], hv.w, p1);
            hv = h2p[i];
            p2 = fmaf(wvv[0], hv.x, p2); p2 = fmaf(wvv[1], hv.y, p2);
            p2 = fmaf(wvv[2], hv.z, p2); p2 = fmaf(wvv[3], hv.w, p2);
            hv = h3p[i];
            p3 = fmaf(wvv[0], hv.x, p3); p3 = fmaf(wvv[1], hv.y, p3);
            p3 = fmaf(wvv[2], hv.z, p3); p3 = fmaf(wvv[3], hv.w, p3);
        }
        float a0 = p0 + __shfl_xor(p0, 1, 64) + gv.x;
        float a1 = p1 + __shfl_xor(p1, 1, 64) + gv.y;
        float a2 = p2 + __shfl_xor(p2, 1, 64) + gv.z;
        float a3 = p3 + __shfl_xor(p3, 1, 64) + gv.w;
        gv = gvn;

        // ---- 4x4 transpose across q-quad (static butterflies) ----
        {
            float s0 = qb0 ? a0 : a1;
            float s1 = qb0 ? a2 : a3;
            float r0 = __shfl_xor(s0, 2, 64);
            float r1 = __shfl_xor(s1, 2, 64);
            if (qb0) { a0 = r0; a2 = r1; } else { a1 = r0; a3 = r1; }
        }
        {
            float s0 = qb1 ? a0 : a2;
            float s1 = qb1 ? a1 : a3;
            float r0 = __shfl_xor(s0, 4, 64);
            float r1 = __shfl_xor(s1, 4, 64);
            if (qb1) { a0 = r0; a1 = r1; } else { a2 = r0; a3 = r1; }
        }

        c = (1.f / (1.f + expf(-a1))) * c + (1.f / (1.f + expf(-a0))) * tanhf(a2);
        const float h = (1.f / (1.f + expf(-a3))) * tanhf(c);

        if (s == 0) {
            const int t_orig = dir ? (LSEQ - 1 - t) : t;
            const unsigned long long pkt =
                ((unsigned long long)(unsigned int)(t + 1) << 32)
                | (unsigned long long)__float_as_uint(h);
            __hip_atomic_store(
                &htag[(((size_t)wslot * 2 + dir) * BATCH + bbase + q) * HID + ee],
                pkt, __ATOMIC_RELAXED, __HIP_MEMORY_SCOPE_AGENT);
            hs[((size_t)(dir * LSEQ + t_orig) * BATCH + bbase + q) * HID + ee] = h;
        }
    }
    if (s == 0)
        cbuf[((size_t)dir * BATCH + bbase + q) * HID + ee] = c;
}

// ---------------- output projection: logits[b][t][11] ----------------
__global__ void __launch_bounds__(256) logits_k(
    const float* __restrict__ hs, const float* __restrict__ Wout,
    const float* __restrict__ bout, float* __restrict__ logits)
{
    const int tid = threadIdx.x;
    const int rt = tid >> 4, tg = tid & 15;
    __shared__ float hrow[16][516];
    __shared__ float Wl[NTAG][516];
    const int rbase = blockIdx.x * 16;

#pragma unroll
    for (int i = 0; i < 8; i++) {
        int u  = tid + i * 256;
        int rr = u >> 7, c4 = u & 127;
        int r_g = rbase + rr;
        int b = r_g >> 9, t = r_g & 511;
        int d = (c4 >= 64) ? 1 : 0, k4 = c4 & 63;
        float4 hv = ((const float4*)hs)[(((size_t)d * LSEQ + t) * BATCH + b) * 64 + k4];
        *(float4*)&hrow[rr][c4 * 4] = hv;
    }
    for (int u = tid; u < NTAG * 128; u += 256) {
        int row = u >> 7, c4 = u & 127;
        float4 wv = ((const float4*)Wout)[(size_t)row * 128 + c4];
        *(float4*)&Wl[row][c4 * 4] = wv;
    }
    __syncthreads();

    if (tg < NTAG) {
        const float4* hp = (const float4*)&hrow[rt][0];
        const float4* wp = (const float4*)&Wl[tg][0];
        float acc = 0.f;
#pragma unroll 4
        for (int k = 0; k < 128; k++) {
            float4 h = hp[k], ww = wp[k];
            acc = fmaf(h.x, ww.x, acc); acc = fmaf(h.y, ww.y, acc);
            acc = fmaf(h.z, ww.z, acc); acc = fmaf(h.w, ww.w, acc);
        }
        int r_g = rbase + rt;
        logits[(size_t)r_g * NTAG + tg] = acc + bout[tg];
    }
}

// ---------------- Viterbi (one wave per batch element) ----------------
__global__ void __launch_bounds__(64) viterbi_k(
    const float* __restrict__ logits, const float* __restrict__ trans,
    float* __restrict__ out)
{
    const int b = blockIdx.x, lane = threadIdx.x;
    __shared__ float lgl[LSEQ * NTAG];
    __shared__ unsigned char bp[LSEQ][16];
    __shared__ float pathf[LSEQ];

    {
        const float4* src = (const float4*)(logits + (size_t)b * LSEQ * NTAG);
        float4* dst = (float4*)lgl;
        for (int u = lane; u < (LSEQ * NTAG) / 4; u += 64) dst[u] = src[u];
    }
    float tcol[NTAG];
    if (lane < NTAG) {
#pragma unroll
        for (int i = 0; i < NTAG; i++) tcol[i] = trans[i * NTAG + lane];
    }
    __syncthreads();

    float v = (lane < NTAG) ? lgl[lane] : -1e30f;
    for (int t = 1; t < LSEQ; t++) {
        float best = -1e30f; int bi = 0;
#pragma unroll
        for (int i = 0; i < NTAG; i++) {
            float vi = __shfl(v, i, 64) + tcol[i];
            if (vi > best) { best = vi; bi = i; }   // strict > == first-max
        }
        if (lane < NTAG) {
            v = lgl[t * NTAG + lane] + best;
            bp[t][lane] = (unsigned char)bi;
        }
    }
    float bestv = -1e30f; int bestj = 0;
#pragma unroll
    for (int j = 0; j < NTAG; j++) {
        float vj = __shfl(v, j, 64);
        if (vj > bestv) { bestv = vj; bestj = j; }
    }
    if (lane == 0) {
        out[b] = bestv;
        int st = bestj;
        pathf[LSEQ - 1] = (float)st;
        for (int t = LSEQ - 1; t >= 1; t--) { st = bp[t][st]; pathf[t - 1] = (float)st; }
    }
    __syncthreads();
    for (int t = lane; t < LSEQ; t += 64)
        out[BATCH + (size_t)b * LSEQ + t] = pathf[t];
}

// ---------------- host ----------------
extern "C" void kernel_launch(void* const* d_in, const int* in_sizes, int n_in,
                              void* d_out, int out_size, void* d_ws, size_t ws_size,
                              hipStream_t stream)
{
    (void)in_sizes; (void)n_in; (void)out_size;
    const int*   sent  = (const int*)  d_in[0];
    const float* emb   = (const float*)d_in[1];
    const float* Wihf  = (const float*)d_in[2];
    const float* Whhf  = (const float*)d_in[3];
    const float* bf    = (const float*)d_in[4];
    const float* Wihb  = (const float*)d_in[5];
    const float* Whhb  = (const float*)d_in[6];
    const float* bb    = (const float*)d_in[7];
    const float* Wout  = (const float*)d_in[8];
    const float* bout  = (const float*)d_in[9];
    const float* trans = (const float*)d_in[10];
    const float* h0    = (const float*)d_in[11];
    const float* c0    = (const float*)d_in[12];
    float* out = (float*)d_out;

    // ws (floats): Gin[CT*131072] | hs[16777216] | htag[262144] | cbuf[32768]
    //            | logits[360448] | embb[4096000] | w16f[131072] | w16b[131072]
    const size_t fixed = 16777216ull + 262144ull + 32768ull + 360448ull
                       + 4096000ull + 131072ull + 131072ull;
    int CT = LSEQ;
    while (CT > 8 && ((size_t)CT * 131072ull + fixed) * 4ull > ws_size) CT >>= 1;

    float* ws = (float*)d_ws;
    size_t off = 0;
    float* Gin  = ws + off; off += (size_t)CT * 131072ull;
    float* hs   = ws + off; off += 16777216ull;
    unsigned long long* htag = (unsigned long long*)(ws + off); off += 262144ull;
    float* cbuf = ws + off; off += 32768ull;
    float* lgts = ws + off; off += 360448ull;
    u16* embb = (u16*)(ws + off); off += 4096000ull;
    u16* w16f = (u16*)(ws + off); off += 131072ull;
    u16* w16b = (u16*)(ws + off); off += 131072ull;

    hipLaunchKernelGGL(cvt_bf16, dim3(2048), dim3(256), 0, stream,
                       emb, embb, (32000 * 256) / 4);
    hipLaunchKernelGGL(cvt_bf16, dim3(256), dim3(256), 0, stream,
                       Wihf, w16f, (1024 * 256) / 4);
    hipLaunchKernelGGL(cvt_bf16, dim3(256), dim3(256), 0, stream,
                       Wihb, w16b, (1024 * 256) / 4);

    const int nch = LSEQ / CT;
    for (int c = 0; c < nch; c++) {
        int t0 = c * CT;
        hipLaunchKernelGGL(gemm_in, dim3(CT / 2, 8, 2), dim3(256), 0, stream,
                           sent, embb, w16f, w16b, bf, bb, Gin, t0, CT);
        hipLaunchKernelGGL(lstm_rec, dim3(256), dim3(256), 0, stream,
                           Gin, Whhf, Whhb, h0, c0, hs, htag, cbuf, t0, CT);
    }
    hipLaunchKernelGGL(logits_k, dim3((BATCH * LSEQ) / 16), dim3(256), 0, stream,
                       hs, Wout, bout, lgts);
    hipLaunchKernelGGL(viterbi_k, dim3(BATCH), dim3(64), 0, stream,
                       lgts, trans, out);
}